// Round 7
// baseline (197861.487 us; speedup 1.0000x reference)
//
#include <hip/hip_runtime.h>
#include <stdint.h>

#define S_LEN 2048
#define BATCH 32
#define EDIM  512
#define HDIM  512
#define G3    1536          // 3 * HDIM gate rows
#define NTHREADS 512        // 8 waves: each owns 64 h-columns

typedef __attribute__((ext_vector_type(8))) short bf16x8;  // 8 bf16 = 4 VGPRs
typedef __attribute__((ext_vector_type(8))) float f32x8;
typedef __attribute__((ext_vector_type(4))) float f32x4;

__device__ __forceinline__ unsigned short f2bf(float f) {
    union { float f; unsigned int i; } v; v.f = f;
    unsigned int u = v.i;
    return (unsigned short)((u + 0x7fffu + ((u >> 16) & 1u)) >> 16);  // RNE
}
__device__ __forceinline__ bf16x8 cvt8(f32x8 v) {
    bf16x8 r;
#pragma unroll
    for (int i = 0; i < 8; ++i) r[i] = (short)f2bf(v[i]);
    return r;
}

// ---------------------------------------------------------------------------
// k0: convert the 4 weight matrices fp32 -> bf16 into ws: [4][1536][512]
//     m: 0=Wih_f, 1=Whh_f, 2=Wih_b, 3=Whh_b.  grid(384,4) x 256: exact cover.
// ---------------------------------------------------------------------------
__global__ void wconvert(const float* __restrict__ w0, const float* __restrict__ w1,
                         const float* __restrict__ w2, const float* __restrict__ w3,
                         unsigned short* __restrict__ o) {
    const int m = blockIdx.y;                          // 0..3
    const int j = blockIdx.x * blockDim.x + threadIdx.x;  // vec8 idx, 0..98303
    const float* src = (m == 0) ? w0 : (m == 1) ? w1 : (m == 2) ? w2 : w3;
    f32x8 v = *(const f32x8*)(src + (size_t)j * 8);
    *(bf16x8*)(o + (size_t)m * (G3 * EDIM) + (size_t)j * 8) = cvt8(v);
}

// ---------------------------------------------------------------------------
// k1: batch-partitioned GRU — ZERO cross-WG communication.
// 4 WGs (dir = wg>>1, mt = wg&1): each owns 16 batch rows x full H=512.
// 8 waves; wave w owns h-cols [w*64, w*64+64) as 4 triples of 16 cols.
// Per step per wave: 4 triples x { 6 B-frag streams (r/z/n x Wih/Whh) x 16 kt
// MFMAs } + in-register pointwise. h(t) round-trips a WG-private global
// buffer (L1-coherent, ordered by __syncthreads). Weights stream bf16 from
// the XCD's L2 (3 MB/dir, L2-resident).
// ---------------------------------------------------------------------------
__global__ void __launch_bounds__(NTHREADS, 2)
gru_gemm(const float* __restrict__ xseq,              // [S][B][E] fp32
         const unsigned short* __restrict__ Wbf,      // [4][1536][512] bf16
         const float* __restrict__ bih_f, const float* __restrict__ bhh_f,
         const float* __restrict__ bih_b, const float* __restrict__ bhh_b,
         float* __restrict__ out,                     // [B][2H] fp32
         unsigned short* __restrict__ hbuf)           // [4][16][512] bf16
{
    const int wg   = blockIdx.x;        // 0..3
    const int dir  = wg >> 1;
    const int mt   = wg & 1;            // batch half: rows mt*16 .. mt*16+15
    const int tid  = threadIdx.x;
    const int lane = tid & 63;
    const int w    = tid >> 6;          // wave 0..7
    const int l15  = lane & 15;
    const int q8   = (lane >> 4) * 8;   // A/B-frag k-offset: 0,8,16,24
    const int rj   = (lane >> 4) * 4;   // C-frag row base: 0,4,8,12

    const unsigned short* Wih = Wbf + (size_t)(dir * 2 + 0) * (G3 * EDIM);
    const unsigned short* Whh = Wbf + (size_t)(dir * 2 + 1) * (G3 * EDIM);
    const float* bih = dir ? bih_b : bih_f;
    const float* bhh = dir ? bhh_b : bhh_f;
    unsigned short* hb = hbuf + (size_t)wg * (16 * HDIM);   // WG-private

    // ---- per-lane biases for the 4 triples (r/z combined: reassoc only) ----
    float bsr[4], bsz[4], bin_[4], bhn[4];
#pragma unroll
    for (int ct = 0; ct < 4; ++ct) {
        const int c = w * 64 + ct * 16 + l15;
        bsr[ct]  = bih[c] + bhh[c];
        bsz[ct]  = bih[512 + c] + bhh[512 + c];
        bin_[ct] = bih[1024 + c];
        bhn[ct]  = bhh[1024 + c];
    }

    // ---- state: h fp32 master per lane, bf16 A-frags of h and x ----
    float hreg[16];                       // [ct*4 + j] = h[rj+j][c0+l15]
#pragma unroll
    for (int i = 0; i < 16; ++i) hreg[i] = 0.0f;
    bf16x8 ha[16];                        // h(t-1) A-frags (m=l15, k=kt*32+q8)
#pragma unroll
    for (int i = 0; i < 16; ++i) ha[i] = bf16x8{};   // h0 = 0
    bf16x8 xa[16];                        // x(t) A-frags
    {
        const int tx0 = dir ? (S_LEN - 1) : 0;
        const float* xp = xseq + (size_t)tx0 * (BATCH * EDIM)
                          + (size_t)(mt * 16 + l15) * EDIM + q8;
#pragma unroll
        for (int kt = 0; kt < 16; ++kt)
            xa[kt] = cvt8(*(const f32x8*)(xp + kt * 32));
    }

    const size_t gstep = (size_t)512 * EDIM;   // one gate block of W rows

    for (int t = 0; t < S_LEN; ++t) {
        const bool last = (t == S_LEN - 1);

        // ================= phase 1: GEMM + pointwise, per triple =============
#pragma unroll
        for (int ct = 0; ct < 4; ++ct) {
            const int c0 = w * 64 + ct * 16;
            const unsigned short* pr = Wih + (size_t)(c0 + l15) * EDIM + q8;
            const unsigned short* qr = Whh + (size_t)(c0 + l15) * HDIM + q8;

            f32x4 axr = {0.f, 0.f, 0.f, 0.f}, ahr = {0.f, 0.f, 0.f, 0.f};
            f32x4 axz = {0.f, 0.f, 0.f, 0.f}, ahz = {0.f, 0.f, 0.f, 0.f};
            f32x4 axn = {0.f, 0.f, 0.f, 0.f}, ahn = {0.f, 0.f, 0.f, 0.f};
#pragma unroll
            for (int kt = 0; kt < 16; ++kt) {
                const int o = kt * 32;
                const bf16x8 br_ = *(const bf16x8*)(pr + o);
                const bf16x8 cr_ = *(const bf16x8*)(qr + o);
                const bf16x8 bz_ = *(const bf16x8*)(pr + gstep + o);
                const bf16x8 cz_ = *(const bf16x8*)(qr + gstep + o);
                const bf16x8 bn_ = *(const bf16x8*)(pr + 2 * gstep + o);
                const bf16x8 cn_ = *(const bf16x8*)(qr + 2 * gstep + o);
                axr = __builtin_amdgcn_mfma_f32_16x16x32_bf16(xa[kt], br_, axr, 0, 0, 0);
                ahr = __builtin_amdgcn_mfma_f32_16x16x32_bf16(ha[kt], cr_, ahr, 0, 0, 0);
                axz = __builtin_amdgcn_mfma_f32_16x16x32_bf16(xa[kt], bz_, axz, 0, 0, 0);
                ahz = __builtin_amdgcn_mfma_f32_16x16x32_bf16(ha[kt], cz_, ahz, 0, 0, 0);
                axn = __builtin_amdgcn_mfma_f32_16x16x32_bf16(xa[kt], bn_, axn, 0, 0, 0);
                ahn = __builtin_amdgcn_mfma_f32_16x16x32_bf16(ha[kt], cn_, ahn, 0, 0, 0);
            }

            // ---- pointwise GRU cell, all in registers (C: col=l15, row=rj+j)
#pragma unroll
            for (int j = 0; j < 4; ++j) {
                const float rr  = 1.f / (1.f + __expf(-(axr[j] + ahr[j] + bsr[ct])));
                const float zz  = 1.f / (1.f + __expf(-(axz[j] + ahz[j] + bsz[ct])));
                const float xn  = axn[j] + bin_[ct];
                const float hn  = ahn[j] + bhn[ct];
                const float pre = xn + rr * hn;
                const float n_  = 2.f / (1.f + __expf(-2.f * pre)) - 1.f;  // tanh
                const float hnew = (1.f - zz) * n_ + zz * hreg[ct * 4 + j];
                hreg[ct * 4 + j] = hnew;
                if (!last) {
                    // pack adjacent cols (lane pairs) -> one dword plain store
                    const float ho = __shfl_xor(hnew, 1);
                    if ((l15 & 1) == 0) {
                        const unsigned int pack = (unsigned int)f2bf(hnew)
                                                | ((unsigned int)f2bf(ho) << 16);
                        *(unsigned int*)(hb + (size_t)(rj + j) * HDIM + c0 + l15) = pack;
                    }
                } else {
                    out[(size_t)(mt * 16 + rj + j) * (2 * HDIM)
                        + dir * HDIM + c0 + l15] = hnew;
                }
            }
        }
        if (last) break;

        __syncthreads();   // h(t) stores drained & visible WG-wide

        // ============ phase 2: rebuild ha from hb, xa from x(t+1) ============
        {
            const unsigned short* hp = hb + (size_t)l15 * HDIM + q8;
#pragma unroll
            for (int kt = 0; kt < 16; ++kt)
                ha[kt] = *(const bf16x8*)(hp + kt * 32);

            const int txn = dir ? (S_LEN - 2 - t) : (t + 1);
            const float* xq = xseq + (size_t)txn * (BATCH * EDIM)
                              + (size_t)(mt * 16 + l15) * EDIM + q8;
#pragma unroll
            for (int kt = 0; kt < 16; ++kt)
                xa[kt] = cvt8(*(const f32x8*)(xq + kt * 32));
        }

        __syncthreads();   // all hb reads done before next step overwrites
    }
}

extern "C" void kernel_launch(void* const* d_in, const int* in_sizes, int n_in,
                              void* d_out, int out_size, void* d_ws, size_t ws_size,
                              hipStream_t stream) {
    // setup_inputs order: seq_length, embedding_seq, Wih_f, Whh_f, bih_f, bhh_f,
    //                     Wih_b, Whh_b, bih_b, bhh_b   (float32 tensors)
    const float* xseq  = (const float*)d_in[1];
    const float* Wih_f = (const float*)d_in[2];
    const float* Whh_f = (const float*)d_in[3];
    const float* bih_f = (const float*)d_in[4];
    const float* bhh_f = (const float*)d_in[5];
    const float* Wih_b = (const float*)d_in[6];
    const float* Whh_b = (const float*)d_in[7];
    const float* bih_b = (const float*)d_in[8];
    const float* bhh_b = (const float*)d_in[9];

    // ws layout: [0, 6MB) Wbf bf16 [4][1536][512]; [8MB, 8MB+64K) hbuf
    // (round-1's crash in the >=392MB branch proves ws_size is ample)
    unsigned short* Wbf  = (unsigned short*)d_ws;
    unsigned short* hbuf = (unsigned short*)((char*)d_ws + (8ull << 20));

    hipLaunchKernelGGL(wconvert, dim3(384, 4), dim3(256), 0, stream,
                       Wih_f, Whh_f, Wih_b, Whh_b, Wbf);
    hipLaunchKernelGGL(gru_gemm, dim3(4), dim3(NTHREADS), 0, stream,
                       xseq, Wbf, bih_f, bhh_f, bih_b, bhh_b,
                       (float*)d_out, hbuf);
}

// Round 8
// 10118.430 us; speedup vs baseline: 19.5546x; 19.5546x over previous
//
#include <hip/hip_runtime.h>
#include <stdint.h>

#define S_LEN 2048
#define BATCH 32
#define EDIM  512
#define HDIM  512
#define NSLICE 32      // workgroups per direction (slices of h cols)
#define SCOLS  16      // HDIM / NSLICE : h columns owned per WG
#define NG     48      // 3 gates * SCOLS gate-rows per WG = 3 exact MFMA tiles
#define NTHREADS 512   // 8 waves: (kh 0..3) x (mt 0..1)

typedef __attribute__((ext_vector_type(8))) short bf16x8;  // 8 bf16 = 4 VGPRs
typedef __attribute__((ext_vector_type(8))) float f32x8;
typedef __attribute__((ext_vector_type(4))) float f32x4;

__device__ __forceinline__ unsigned short f2bf(float f) {
    union { float f; unsigned int i; } v; v.f = f;
    unsigned int u = v.i;
    return (unsigned short)((u + 0x7fffu + ((u >> 16) & 1u)) >> 16);  // RNE
}
__device__ __forceinline__ bf16x8 cvt8(f32x8 v) {
    bf16x8 r;
#pragma unroll
    for (int i = 0; i < 8; ++i) r[i] = (short)f2bf(v[i]);
    return r;
}

// 64 WGs x 512 threads, 1 WG/CU. dir = wg>>5, slice = wg&31.
// v8 = v4's proven sc1/flag protocol on a K-split geometry:
//   wave (kh, mt): partial GEMM over K-quarter kh (128 of 512) for batch-half
//   mt, ALL 48 gate-cols (3 tiles). Partials summed in LDS, pointwise as v4.
// Why: per-wave ha = 4KB with ZERO duplication (h MALL traffic 8->2 MB/step),
// fan-in 32 (straggler + poll storm halved), carried regs 128 (wf48 hf48
// xa16 ha16) — pinned to the 256 cap via waves_per_eu(2,2) so the v7
// spill-to-scratch failure mode cannot recur.
__global__ void
__attribute__((amdgpu_flat_work_group_size(NTHREADS, NTHREADS)))
__attribute__((amdgpu_waves_per_eu(2, 2)))
gru_persistent(const float* __restrict__ xseq,   // [S][B][E] fp32
               const float* __restrict__ Wih_f,
               const float* __restrict__ Whh_f,
               const float* __restrict__ bih_f,
               const float* __restrict__ bhh_f,
               const float* __restrict__ Wih_b,
               const float* __restrict__ Whh_b,
               const float* __restrict__ bih_b,
               const float* __restrict__ bhh_b,
               float* __restrict__ out,            // [B][2H] fp32
               int* __restrict__ flags,            // [2][32]
               unsigned short* __restrict__ h_buf) // [2 buf][2 dir][B][H] bf16
{
    const int wg   = blockIdx.x;
    const int dir  = wg >> 5;
    const int sl   = wg & 31;
    const int tid  = threadIdx.x;
    const int lane = tid & 63;
    const int wv   = tid >> 6;      // 0..7
    const int kh   = wv & 3;        // K-quarter: k in [kh*128, kh*128+128)
    const int mtw  = wv >> 2;       // batch half: rows mtw*16 .. mtw*16+15
    const int l15  = lane & 15;
    const int q8   = (lane >> 4) * 8;   // frag k-offset within 32-wide window
    const int rj   = (lane >> 4) * 4;   // C-frag row base: 0,4,8,12

    const float* Wih = dir ? Wih_b : Wih_f;
    const float* Whh = dir ? Whh_b : Whh_f;
    const float* bih = dir ? bih_b : bih_f;
    const float* bhh = dir ? bhh_b : bhh_f;

    __shared__ float gxl[4][BATCH][NG + 1];   // per-kh partials, +1 pad
    __shared__ float ghl[4][BATCH][NG + 1];
    __shared__ float hloc[BATCH][SCOLS];      // fp32 master copy of our slice
    __shared__ float bih_s[NG], bhh_s[NG];

    // ---- persistent weight B-fragments (fp32 -> bf16 RNE once) ----
    // tile ti = gate (r,z,n); B-frag: n = l15, k = kh*128 + kt*32 + q8 + j
    bf16x8 wf[3][4], hf[3][4];    // [ti][kt] : 24+24 frags = 96+96 VGPRs... 48+48
    {
#pragma unroll
        for (int ti = 0; ti < 3; ++ti) {
            const int row = ti * HDIM + sl * SCOLS + l15;   // gate*512 + col
#pragma unroll
            for (int kt = 0; kt < 4; ++kt) {
                const int k = kh * 128 + kt * 32 + q8;
                wf[ti][kt] = cvt8(*(const f32x8*)(Wih + (size_t)row * EDIM + k));
                hf[ti][kt] = cvt8(*(const f32x8*)(Whh + (size_t)row * HDIM + k));
            }
        }
    }
    if (tid < NG) {
        const int row = (tid >> 4) * HDIM + sl * SCOLS + (tid & 15);
        bih_s[tid] = bih[row];
        bhh_s[tid] = bhh[row];
    }
    hloc[tid >> 4][tid & 15] = 0.0f;   // 512 items, 1:1 — h0 = 0
    __syncthreads();

    // A-frag addressing: m-row = mtw*16 + l15, k = kh*128 + kt*32 + q8 + j
    const int m_row = mtw * 16 + l15;
    const int kbase = kh * 128;
    int* myflags = flags + dir * NSLICE;

    const int b_pw = tid >> 4;    // pointwise thread -> (batch, col) 1:1
    const int c_pw = tid & 15;

    // ---- prologue: xa = x(t=0) frags; ha = 0 (h0 = 0, no load at t=0) ----
    bf16x8 xa[4], ha[4];
    {
        const int tx0 = dir ? (S_LEN - 1) : 0;
        const float* xp = xseq + (size_t)tx0 * (BATCH * EDIM)
                          + (size_t)m_row * EDIM + kbase + q8;
#pragma unroll
        for (int kt = 0; kt < 4; ++kt) {
            xa[kt] = cvt8(*(const f32x8*)(xp + kt * 32));
            ha[kt] = bf16x8{};
        }
    }

    for (int t = 0; t < S_LEN; ++t) {
        // ---- gx partials = x(t) @ Wih^T : registers only, pre-poll ----
        f32x4 accx[3] = {{0.f,0.f,0.f,0.f},{0.f,0.f,0.f,0.f},{0.f,0.f,0.f,0.f}};
#pragma unroll
        for (int ti = 0; ti < 3; ++ti)
#pragma unroll
            for (int kt = 0; kt < 4; ++kt)
                accx[ti] = __builtin_amdgcn_mfma_f32_16x16x32_bf16(
                               xa[kt], wf[ti][kt], accx[ti], 0, 0, 0);

        if (t > 0) {
            // ---- wait for all 32 slices of h(t-1) (relaxed, sc1) ----
            int* fp = myflags + (lane & 31);
            for (;;) {
                int f = __hip_atomic_load(fp, __ATOMIC_RELAXED,
                                          __HIP_MEMORY_SCOPE_AGENT);
                if (__all(f >= t)) break;
            }
            // ---- load our 4KB of h(t-1) from LLC (sc1), proven pattern ----
            const unsigned short* hp = h_buf
                + ((size_t)((t & 1) * 2 + dir)) * (BATCH * HDIM)
                + (size_t)m_row * HDIM + kbase + q8;
            asm volatile(
                "global_load_dwordx4 %0, %4, off sc1\n\t"
                "global_load_dwordx4 %1, %4, off offset:64  sc1\n\t"
                "global_load_dwordx4 %2, %4, off offset:128 sc1\n\t"
                "global_load_dwordx4 %3, %4, off offset:192 sc1\n\t"
                "s_waitcnt vmcnt(0)"
                : "=v"(ha[0]), "=v"(ha[1]), "=v"(ha[2]), "=v"(ha[3])
                : "v"(hp)
                : "memory");
        }

        // ---- gh partials = h(t-1) @ Whh^T ----
        f32x4 acch[3] = {{0.f,0.f,0.f,0.f},{0.f,0.f,0.f,0.f},{0.f,0.f,0.f,0.f}};
#pragma unroll
        for (int ti = 0; ti < 3; ++ti)
#pragma unroll
            for (int kt = 0; kt < 4; ++kt)
                acch[ti] = __builtin_amdgcn_mfma_f32_16x16x32_bf16(
                               ha[kt], hf[ti][kt], acch[ti], 0, 0, 0);

        // ---- C-layout (col=l15, row=rj+j) -> per-kh LDS partial slabs ----
#pragma unroll
        for (int ti = 0; ti < 3; ++ti) {
            const int n = ti * 16 + l15;
#pragma unroll
            for (int j = 0; j < 4; ++j) {
                gxl[kh][mtw * 16 + rj + j][n] = accx[ti][j];
                ghl[kh][mtw * 16 + rj + j][n] = acch[ti][j];
            }
        }
        __syncthreads();

        // ---- pointwise GRU cell: sum 4 partials, v4 formulas verbatim ----
        {
            const int b = b_pw, c = c_pw;
            float gxr = gxl[0][b][c]      + gxl[1][b][c]      + gxl[2][b][c]      + gxl[3][b][c];
            float ghr = ghl[0][b][c]      + ghl[1][b][c]      + ghl[2][b][c]      + ghl[3][b][c];
            float gxz = gxl[0][b][16 + c] + gxl[1][b][16 + c] + gxl[2][b][16 + c] + gxl[3][b][16 + c];
            float ghz = ghl[0][b][16 + c] + ghl[1][b][16 + c] + ghl[2][b][16 + c] + ghl[3][b][16 + c];
            float gxn = gxl[0][b][32 + c] + gxl[1][b][32 + c] + gxl[2][b][32 + c] + gxl[3][b][32 + c];
            float ghn = ghl[0][b][32 + c] + ghl[1][b][32 + c] + ghl[2][b][32 + c] + ghl[3][b][32 + c];
            const float xr = gxr + bih_s[c];
            const float hr = ghr + bhh_s[c];
            const float xz = gxz + bih_s[16 + c];
            const float hz = ghz + bhh_s[16 + c];
            const float xn = gxn + bih_s[32 + c];
            const float hn = ghn + bhh_s[32 + c];
            const float r  = 1.f / (1.f + __expf(-(xr + hr)));
            const float z  = 1.f / (1.f + __expf(-(xz + hz)));
            const float pre = xn + r * hn;
            const float n_  = 2.f / (1.f + __expf(-2.f * pre)) - 1.f;  // tanh
            const float hnew = (1.f - z) * n_ + z * hloc[b][c];
            hloc[b][c] = hnew;
            if (t < S_LEN - 1) {
                // pair adjacent cols -> one dword sc1 (write-through to LLC)
                const float hother = __shfl_xor(hnew, 1);
                if ((c & 1) == 0) {
                    unsigned int pack = (unsigned int)f2bf(hnew)
                                      | ((unsigned int)f2bf(hother) << 16);
                    unsigned int* dst = (unsigned int*)(h_buf
                        + ((size_t)(((t + 1) & 1) * 2 + dir)) * (BATCH * HDIM)
                        + (size_t)b * HDIM + sl * SCOLS + c);
                    asm volatile("global_store_dword %0, %1, off sc1"
                                 :: "v"(dst), "v"(pack) : "memory");
                }
            } else {
                out[(size_t)b * (2 * HDIM) + dir * HDIM + sl * SCOLS + c] = hnew;
            }
        }
        // drain our sc1 stores to the LLC before the barrier, then publish
        asm volatile("s_waitcnt vmcnt(0)" ::: "memory");
        __syncthreads();

        if (t < S_LEN - 1) {
            if (tid == 0) {
                __hip_atomic_store(&myflags[sl], t + 1, __ATOMIC_RELAXED,
                                   __HIP_MEMORY_SCOPE_AGENT);
            }
            // ---- tail: load + cvt x(t+1); RT hides in next flag-wait ----
            const int txn = dir ? (S_LEN - 2 - t) : (t + 1);
            const float* xq = xseq + (size_t)txn * (BATCH * EDIM)
                              + (size_t)m_row * EDIM + kbase + q8;
#pragma unroll
            for (int kt = 0; kt < 4; ++kt) {
                f32x8 v = *(const f32x8*)(xq + kt * 32);
                xa[kt] = cvt8(v);
            }
        }
    }
}

extern "C" void kernel_launch(void* const* d_in, const int* in_sizes, int n_in,
                              void* d_out, int out_size, void* d_ws, size_t ws_size,
                              hipStream_t stream) {
    // setup_inputs order: seq_length, embedding_seq, Wih_f, Whh_f, bih_f, bhh_f,
    //                     Wih_b, Whh_b, bih_b, bhh_b   (float32 tensors)
    const float* xseq  = (const float*)d_in[1];
    const float* Wih_f = (const float*)d_in[2];
    const float* Whh_f = (const float*)d_in[3];
    const float* bih_f = (const float*)d_in[4];
    const float* bhh_f = (const float*)d_in[5];
    const float* Wih_b = (const float*)d_in[6];
    const float* Whh_b = (const float*)d_in[7];
    const float* bih_b = (const float*)d_in[8];
    const float* bhh_b = (const float*)d_in[9];

    // ws layout: [0,256) flags int[2][32]; [512, 512+128K) h double buffers
    int* flags = (int*)d_ws;
    unsigned short* h_buf = (unsigned short*)((char*)d_ws + 512);
    const size_t init_bytes = 512 + (size_t)2 * 2 * BATCH * HDIM * sizeof(unsigned short);
    hipMemsetAsync(d_ws, 0, init_bytes, stream);   // zero flags + h0 (graph-safe)

    hipLaunchKernelGGL(gru_persistent, dim3(2 * NSLICE), dim3(NTHREADS), 0, stream,
                       xseq, Wih_f, Whh_f, bih_f, bhh_f,
                       Wih_b, Whh_b, bih_b, bhh_b,
                       (float*)d_out, flags, h_buf);
}